// Round 8
// baseline (189.954 us; speedup 1.0000x reference)
//
#include <hip/hip_runtime.h>
#include <hip/hip_bf16.h>
#include <stdint.h>

// QuantizedConv2d int8: x (32,128,56,56), w (256,128,3,3), pad 1, stride 1.
// Implicit GEMM on v_mfma_i32_32x32x32_i8. M=out-ch, N=pixels, K=9*128=1152.
// R17: MAX-REUSE wave tile. Wave = 128ch x 128px (2 rows x 64px):
// acc[4][2][2] = 256 acc regs. Per ks-step: 4 A + 4 B b128 reads -> 16
// back-to-back MFMAs on independent accs (2.0 MFMA/read; all seven prior
// null schedules were <=1.33). LDS pipe/CU ~8.8us < MFMA 15.4us: MFMA is
// finally the top pipe. Block = 2 waves (128 thr, 4 rows); lx = R12's 6-row
// XOR-swizzled buffer; lw per-tap dbuf; 1 barrier/tap. 79.4 KB LDS -> 2
// blocks/CU -> 4 waves/CU (1/SIMD, ~340 regs/wave). 16-MFMA bursts (586 cyc)
// self-hide operand latency despite 1 wave/SIMD.

#define NB   32
#define CIN  128
#define HO   56
#define WO   56
#define KOUT 256
#define HP   58
#define ROWB (HP * CIN)          // 7424 bytes per padded row

typedef int v4i  __attribute__((ext_vector_type(4)));
typedef int v16i __attribute__((ext_vector_type(16)));

static __device__ __forceinline__ void gload_lds16(const int8_t* g, int8_t* l) {
  __builtin_amdgcn_global_load_lds(
      (const __attribute__((address_space(1))) void*)g,
      (__attribute__((address_space(3))) void*)l, 16, 0, 0);
}

// ---------------- pack x: NCHW int32 -> padded NHWC int8 (int4 reads) --------
__global__ __launch_bounds__(256) void pack_x_kernel(const int* __restrict__ x,
                                                     int8_t* __restrict__ xp) {
  __shared__ int t32[128][57];       // 29,184 B, stride 57 to break conflicts
  const int tid = threadIdx.x;
  const int r = blockIdx.x;          // padded row 0..57
  const int n = blockIdx.y;
  const bool interior = (r >= 1) && (r <= HO);

  if (interior) {
    const int h = r - 1;
    const int* xrow = x + ((size_t)(n * CIN) * HO + h) * WO;  // c stride = 3136 ints
    #pragma unroll
    for (int it = 0; it < 7; ++it) {
      const int j = it * 256 + tid;  // < 1792 = 128 c x 14 w-quads
      const int c = j / 14;
      const int w4 = j - c * 14;
      const int4 v = *reinterpret_cast<const int4*>(xrow + c * 3136 + w4 * 4);
      t32[c][w4 * 4 + 0] = v.x;
      t32[c][w4 * 4 + 1] = v.y;
      t32[c][w4 * 4 + 2] = v.z;
      t32[c][w4 * 4 + 3] = v.w;
    }
  }
  __syncthreads();
  #pragma unroll
  for (int it = 0; it < 8; ++it) {
    const int i = it * 256 + tid;
    if (i < HP * 32) {
      const int w = i >> 5;          // padded col 0..57
      const int c4 = i & 31;
      int vv = 0;
      if (interior && w >= 1 && w <= WO) {
        const int b0 = t32[c4 * 4 + 0][w - 1] & 0xff;
        const int b1 = t32[c4 * 4 + 1][w - 1] & 0xff;
        const int b2 = t32[c4 * 4 + 2][w - 1] & 0xff;
        const int b3 = t32[c4 * 4 + 3][w - 1];
        vv = b0 | (b1 << 8) | (b2 << 16) | (b3 << 24);
      }
      *reinterpret_cast<int*>(xp + ((size_t)(n * HP + r) * HP + w) * CIN + c4 * 4) = vv;
    }
  }
}

// ---- pack w: OIHW int32 -> [ktb(2)][tap(9)][cc(8)][ch(128)] 16B chunks ------
__global__ __launch_bounds__(256) void pack_w_kernel(const int* __restrict__ wgt,
                                                     int8_t* __restrict__ wq) {
  const int wid = blockIdx.x * 256 + threadIdx.x;   // 0..73727 int32 words
  const int wi = wid & 3;
  const int ci = wid >> 2;                          // chunk 0..18431
  const int ktb = ci / 9216;                        // 9216 = 9*8*128
  const int r  = ci - ktb * 9216;
  const int tap = r >> 10;                          // 1024 = 8*128
  const int r2  = r & 1023;
  const int cc  = r2 >> 7;
  const int ch  = r2 & 127;
  const int k_global = ktb * 128 + ch;
  const int cin0 = cc * 16 + wi * 4;
  const int base = (k_global * CIN + cin0) * 9 + tap;  // OIHW, 3x3=9 taps
  const int v0 = wgt[base];
  const int v1 = wgt[base + 9];
  const int v2 = wgt[base + 18];
  const int v3 = wgt[base + 27];
  reinterpret_cast<int*>(wq)[wid] =
      (v0 & 0xff) | ((v1 & 0xff) << 8) | ((v2 & 0xff) << 16) | (v3 << 24);
}

// ------- conv: 128ch x 128px wave tile, 16-deep MFMA bursts ----------------
// grid (14 rg, 32 n, 2 ktb) = 896 blocks, 128 threads = 2 waves.
// Block: 128 out-ch x 4 output rows. Wave wr: rows h0+wr*2 .. +1.
// Per ks: 4 A + 4 B LDS b128 -> 16 MFMA (acc[mt 0..3][lr 0..1][nt 0..1]).
__global__ __launch_bounds__(128, 1) void conv_kernel(const int8_t* __restrict__ xp,
                                                      const int8_t* __restrict__ wq,
                                                      const int* __restrict__ bias,
                                                      const float* __restrict__ wscale,
                                                      int* __restrict__ out) {
  __shared__ __align__(16) int8_t lw[2][8 * 128 * 16];        // 2 x 16,384 B
  __shared__ __align__(16) int8_t lx[(6 * HP + 8) * 8 * 16];  // 45,568 B (+pad)
  __shared__ int   bsh[128];
  __shared__ float ssh[128];

  const int tid = threadIdx.x;
  const int rg = blockIdx.x;           // row group 0..13
  const int n_img = blockIdx.y;
  const int ktb = blockIdx.z;          // 128-ch slice, slowest -> L2 reuse of xp
  const int h0 = rg * 4;

  const int lane = tid & 63;
  const int wr = tid >> 6;             // wave 0..1: rows wr*2, wr*2+1
  const int p0 = lane & 31;
  const int half = lane >> 5;

  const int8_t* xg = xp + ((size_t)(n_img * HP) + h0) * ROWB;
  const int8_t* wqt = wq + (size_t)ktb * (9 * 16384);

  // ---- stage pixels: 6 padded rows = 2784 chunks, XOR swizzle in source ----
  #pragma unroll
  for (int it = 0; it < 22; ++it) {
    const int i = it * 128 + tid;
    if (i < 6 * HP * 8) {
      const int pf = i >> 3;
      const int cc = (i & 7) ^ (pf & 7);
      gload_lds16(xg + pf * CIN + (cc << 4), lx + i * 16);
    }
  }
  // ---- stage weights tap 0: 1024 chunks, 8 per thread ----
  #pragma unroll
  for (int k = 0; k < 8; ++k) {
    const int j = k * 128 + tid;
    gload_lds16(wqt + j * 16, lw[0] + j * 16);
  }
  bsh[tid] = bias[ktb * 128 + tid];
  ssh[tid] = (0.02f * wscale[ktb * 128 + tid]) / 0.05f;  // IN_SCALE*ws/OUT_SCALE
  __syncthreads();

  v16i acc[4][2][2];                   // [mt: 32-ch][lr: row][nt: 32-px]
  #pragma unroll
  for (int mt = 0; mt < 4; ++mt)
    #pragma unroll
    for (int lr = 0; lr < 2; ++lr)
      #pragma unroll
      for (int nt = 0; nt < 2; ++nt)
        #pragma unroll
        for (int e = 0; e < 16; ++e) acc[mt][lr][nt][e] = 0;

  #pragma unroll
  for (int tap = 0; tap < 9; ++tap) {
    // prefetch next tap's weights into the other buffer (drained at barrier)
    if (tap < 8) {
      const int8_t* wsrc = wqt + (tap + 1) * 16384;
      int8_t* ldst = lw[(tap + 1) & 1];
      #pragma unroll
      for (int k = 0; k < 8; ++k) {
        const int j = k * 128 + tid;
        gload_lds16(wsrc + j * 16, ldst + j * 16);
      }
    }
    const int kh = (tap >= 3) + (tap >= 6);
    const int kw = tap - 3 * kh;
    const int8_t* lwt = lw[tap & 1];             // [cc(8)][ch(128)] chunk-major
    #pragma unroll
    for (int ks = 0; ks < 4; ++ks) {
      const int cch = 2 * ks + half;             // k-chunk for this lane
      v4i a[4], b[2][2];
      #pragma unroll
      for (int mt = 0; mt < 4; ++mt)
        a[mt] = *reinterpret_cast<const v4i*>(lwt + cch * 2048 + (mt * 32 + p0) * 16);
      #pragma unroll
      for (int lr = 0; lr < 2; ++lr) {
        const int pfb = (wr * 2 + lr + kh) * HP + kw;
        #pragma unroll
        for (int nt = 0; nt < 2; ++nt) {
          const int pf = pfb + nt * 32 + p0;
          b[lr][nt] = *reinterpret_cast<const v4i*>(lx + pf * CIN + ((cch ^ (pf & 7)) << 4));
        }
      }
      // edge reads (pf > 347) land in the lx pad; they feed only masked w>=56.
      __builtin_amdgcn_s_setprio(1);
      #pragma unroll
      for (int mt = 0; mt < 4; ++mt)
        #pragma unroll
        for (int lr = 0; lr < 2; ++lr)
          #pragma unroll
          for (int nt = 0; nt < 2; ++nt)
            acc[mt][lr][nt] = __builtin_amdgcn_mfma_i32_32x32x32_i8(
                a[mt], b[lr][nt], acc[mt][lr][nt], 0, 0, 0);
      __builtin_amdgcn_s_setprio(0);
    }
    __syncthreads();                   // drains prefetch; guards dbuf swap
  }

  // ---- epilogue: D row = ch = mt*32 + (r&3)+8*(r>>2)+4*half, col = pixel ----
  #pragma unroll
  for (int mt = 0; mt < 4; ++mt) {
    #pragma unroll
    for (int r = 0; r < 16; ++r) {
      const int cl = mt * 32 + (r & 3) + 8 * (r >> 2) + 4 * half;
      const int bi = bsh[cl];
      const float sc = ssh[cl];
      #pragma unroll
      for (int lr = 0; lr < 2; ++lr) {
        const int h = h0 + wr * 2 + lr;
        int* ob = out + (((size_t)(n_img * KOUT + ktb * 128 + cl)) * HO + h) * WO;
        #pragma unroll
        for (int nt = 0; nt < 2; ++nt) {
          const int w = nt * 32 + p0;
          if (w < WO) {
            float v = (float)(acc[mt][lr][nt][r] + bi) * sc;
            v = rintf(v);                        // round-half-even == jnp.round
            v = fminf(fmaxf(v, -128.0f), 127.0f);
            ob[w] = (int)v;
          }
        }
      }
    }
  }
}

extern "C" void kernel_launch(void* const* d_in, const int* in_sizes, int n_in,
                              void* d_out, int out_size, void* d_ws, size_t ws_size,
                              hipStream_t stream) {
  const int* x = (const int*)d_in[0];
  const int* wgt = (const int*)d_in[1];
  const int* bias = (const int*)d_in[2];
  const float* wscale = (const float*)d_in[3];
  int* out = (int*)d_out;

  int8_t* xp = (int8_t*)d_ws;                               // 13,780,992 B
  int8_t* wq = (int8_t*)d_ws + (size_t)NB * HP * ROWB;      // 294,912 B

  pack_x_kernel<<<dim3(HP, NB), 256, 0, stream>>>(x, xp);
  pack_w_kernel<<<288, 256, 0, stream>>>(wgt, wq);
  conv_kernel<<<dim3(14, 32, 2), 128, 0, stream>>>(xp, wq, bias, wscale, out);
}

// Round 9
// 183.413 us; speedup vs baseline: 1.0357x; 1.0357x over previous
//
#include <hip/hip_runtime.h>
#include <hip/hip_bf16.h>
#include <stdint.h>

// QuantizedConv2d int8: x (32,128,56,56), w (256,128,3,3), pad 1, stride 1.
// Implicit GEMM on v_mfma_i32_32x32x32_i8. M=out-ch, N=pixels, K=9*128=1152.
// R18: serial-sum reduction (9 schedule variants all landed at the SUM of
// pipe times; so shrink the terms). (1) 0.75 LDS-reads/MFMA: wave=128ch x
// 64px, acc[4][2], 4A+2B reads -> 8 MFMA. (2) conflict-free B: 2-row-paired
// lx layout (pf-pair in one 256B row, slot = (pf&1)<<3 | cch^((pf>>1)&7)) ->
// consecutive-pf lanes hit 16 quads 2-way (free) instead of 8 quads 4-way;
// measured +2cyc/read eliminated. Linear LDS dest + inverse-permuted global
// source (both-sides involution). (3) per-tap hoisted B addressing.
// Block 128ch x 8 rows, 8 waves, grid (7,32,2)=448; lx 75.3KB + lw 32KB dbuf
// -> 1 block/CU, 2 waves/SIMD. Per-tap weight dbuf, 1 barrier/tap.

#define NB   32
#define CIN  128
#define HO   56
#define WO   56
#define KOUT 256
#define HP   58
#define ROWB (HP * CIN)          // 7424 bytes per padded row

typedef int v4i  __attribute__((ext_vector_type(4)));
typedef int v16i __attribute__((ext_vector_type(16)));

static __device__ __forceinline__ void gload_lds16(const int8_t* g, int8_t* l) {
  __builtin_amdgcn_global_load_lds(
      (const __attribute__((address_space(1))) void*)g,
      (__attribute__((address_space(3))) void*)l, 16, 0, 0);
}

// ---------------- pack x: NCHW int32 -> padded NHWC int8 (int4 reads) --------
__global__ __launch_bounds__(256) void pack_x_kernel(const int* __restrict__ x,
                                                     int8_t* __restrict__ xp) {
  __shared__ int t32[128][57];       // 29,184 B, stride 57 to break conflicts
  const int tid = threadIdx.x;
  const int r = blockIdx.x;          // padded row 0..57
  const int n = blockIdx.y;
  const bool interior = (r >= 1) && (r <= HO);

  if (interior) {
    const int h = r - 1;
    const int* xrow = x + ((size_t)(n * CIN) * HO + h) * WO;  // c stride = 3136 ints
    #pragma unroll
    for (int it = 0; it < 7; ++it) {
      const int j = it * 256 + tid;  // < 1792 = 128 c x 14 w-quads
      const int c = j / 14;
      const int w4 = j - c * 14;
      const int4 v = *reinterpret_cast<const int4*>(xrow + c * 3136 + w4 * 4);
      t32[c][w4 * 4 + 0] = v.x;
      t32[c][w4 * 4 + 1] = v.y;
      t32[c][w4 * 4 + 2] = v.z;
      t32[c][w4 * 4 + 3] = v.w;
    }
  }
  __syncthreads();
  #pragma unroll
  for (int it = 0; it < 8; ++it) {
    const int i = it * 256 + tid;
    if (i < HP * 32) {
      const int w = i >> 5;          // padded col 0..57
      const int c4 = i & 31;
      int vv = 0;
      if (interior && w >= 1 && w <= WO) {
        const int b0 = t32[c4 * 4 + 0][w - 1] & 0xff;
        const int b1 = t32[c4 * 4 + 1][w - 1] & 0xff;
        const int b2 = t32[c4 * 4 + 2][w - 1] & 0xff;
        const int b3 = t32[c4 * 4 + 3][w - 1];
        vv = b0 | (b1 << 8) | (b2 << 16) | (b3 << 24);
      }
      *reinterpret_cast<int*>(xp + ((size_t)(n * HP + r) * HP + w) * CIN + c4 * 4) = vv;
    }
  }
}

// ---- pack w: OIHW int32 -> [ktb(2)][tap(9)][cc(8)][ch(128)] 16B chunks ------
__global__ __launch_bounds__(256) void pack_w_kernel(const int* __restrict__ wgt,
                                                     int8_t* __restrict__ wq) {
  const int wid = blockIdx.x * 256 + threadIdx.x;   // 0..73727 int32 words
  const int wi = wid & 3;
  const int ci = wid >> 2;                          // chunk 0..18431
  const int ktb = ci / 9216;                        // 9216 = 9*8*128
  const int r  = ci - ktb * 9216;
  const int tap = r >> 10;                          // 1024 = 8*128
  const int r2  = r & 1023;
  const int cc  = r2 >> 7;
  const int ch  = r2 & 127;
  const int k_global = ktb * 128 + ch;
  const int cin0 = cc * 16 + wi * 4;
  const int base = (k_global * CIN + cin0) * 9 + tap;  // OIHW, 3x3=9 taps
  const int v0 = wgt[base];
  const int v1 = wgt[base + 9];
  const int v2 = wgt[base + 18];
  const int v3 = wgt[base + 27];
  reinterpret_cast<int*>(wq)[wid] =
      (v0 & 0xff) | ((v1 & 0xff) << 8) | ((v2 & 0xff) << 16) | (v3 << 24);
}

// ------- conv: 0.75 reads/MFMA, conflict-free paired-row lx ----------------
// grid (7 rg, 32 n, 2 ktb) = 448 blocks, 512 threads = 8 waves (1 row each).
// Block: 128 out-ch x 8 output rows. Wave wr: row h0+wr, 128 ch x 64 px.
// acc[4][2] = 128 regs. Per ks: 4 A + 2 B LDS b128 -> 8 MFMA.
__global__ __launch_bounds__(512, 2) void conv_kernel(const int8_t* __restrict__ xp,
                                                      const int8_t* __restrict__ wq,
                                                      const int* __restrict__ bias,
                                                      const float* __restrict__ wscale,
                                                      int* __restrict__ out) {
  __shared__ __align__(16) int8_t lw[2][8 * 128 * 16];   // 2 x 16,384 B
  __shared__ __align__(16) int8_t lx[4704 * 16];         // 75,264 B (10 rows + pad)
  __shared__ int   bsh[128];
  __shared__ float ssh[128];

  const int tid = threadIdx.x;
  const int rg = blockIdx.x;           // row group 0..6 (8 rows each)
  const int n_img = blockIdx.y;
  const int ktb = blockIdx.z;          // 128-ch slice, slowest -> L2 reuse of xp
  const int h0 = rg * 8;

  const int lane = tid & 63;
  const int wr = tid >> 6;             // wave = output row 0..7
  const int p0 = lane & 31;
  const int half = lane >> 5;

  const int8_t* xg = xp + ((size_t)(n_img * HP) + h0) * ROWB;
  const int8_t* wqt = wq + (size_t)ktb * (9 * 16384);

  // ---- stage pixels: 10 padded rows = 4640 chunks, paired-row layout ----
  // dest chunk i: qf=i>>4, s=i&15 -> pf = qf*2 + (s>>3), cc = (s&7) ^ (qf&7).
  // (read side applies the same involution; rule both-sides-or-neither)
  #pragma unroll
  for (int it = 0; it < 10; ++it) {
    const int i = it * 512 + tid;
    if (i < 4640) {
      const int qf = i >> 4;
      const int s = i & 15;
      const int pf = qf * 2 + (s >> 3);
      const int cc = (s & 7) ^ (qf & 7);
      gload_lds16(xg + pf * CIN + (cc << 4), lx + i * 16);
    }
  }
  // ---- stage weights tap 0 ----
  gload_lds16(wqt + tid * 16,         lw[0] + tid * 16);
  gload_lds16(wqt + (512 + tid) * 16, lw[0] + (512 + tid) * 16);
  if (tid < 128) {
    const int ch = ktb * 128 + tid;
    bsh[tid] = bias[ch];
    ssh[tid] = (0.02f * wscale[ch]) / 0.05f;   // IN_SCALE * ws / OUT_SCALE
  }
  __syncthreads();

  v16i acc[4][2];                      // [mt: 32-ch tile][nt: 32-px tile]
  #pragma unroll
  for (int mt = 0; mt < 4; ++mt)
    #pragma unroll
    for (int nt = 0; nt < 2; ++nt)
      #pragma unroll
      for (int e = 0; e < 16; ++e) acc[mt][nt][e] = 0;

  #pragma unroll
  for (int tap = 0; tap < 9; ++tap) {
    // prefetch next tap's weights into the other buffer (drained at barrier)
    if (tap < 8) {
      const int8_t* wsrc = wqt + (tap + 1) * 16384;
      int8_t* ldst = lw[(tap + 1) & 1];
      gload_lds16(wsrc + tid * 16,         ldst + tid * 16);
      gload_lds16(wsrc + (512 + tid) * 16, ldst + (512 + tid) * 16);
    }
    const int kh = (tap >= 3) + (tap >= 6);
    const int kw = tap - 3 * kh;
    const int8_t* lwt = lw[tap & 1];             // [cc(8)][ch(128)] chunk-major
    // hoisted B addressing: pf -> byte = (pf>>1)*256 + (pf&1)*128 + slot*16
    const int pf0 = (wr + kh) * HP + kw + p0;
    const int pf1 = pf0 + 32;
    const int8_t* bbase0 = lx + ((pf0 >> 1) << 8) + ((pf0 & 1) << 7);
    const int8_t* bbase1 = lx + ((pf1 >> 1) << 8) + ((pf1 & 1) << 7);
    const int q70 = (pf0 >> 1) & 7;
    const int q71 = (pf1 >> 1) & 7;
    #pragma unroll
    for (int ks = 0; ks < 4; ++ks) {
      const int cch = 2 * ks + half;             // k-chunk for this lane
      v4i a[4];
      #pragma unroll
      for (int mt = 0; mt < 4; ++mt)
        a[mt] = *reinterpret_cast<const v4i*>(lwt + cch * 2048 + (mt * 32 + p0) * 16);
      const v4i b0 = *reinterpret_cast<const v4i*>(bbase0 + ((cch ^ q70) << 4));
      const v4i b1 = *reinterpret_cast<const v4i*>(bbase1 + ((cch ^ q71) << 4));
      // edge reads (pf > 579) land in the lx pad; they feed only masked w>=56.
      __builtin_amdgcn_s_setprio(1);
      #pragma unroll
      for (int mt = 0; mt < 4; ++mt) {
        acc[mt][0] = __builtin_amdgcn_mfma_i32_32x32x32_i8(a[mt], b0, acc[mt][0], 0, 0, 0);
        acc[mt][1] = __builtin_amdgcn_mfma_i32_32x32x32_i8(a[mt], b1, acc[mt][1], 0, 0, 0);
      }
      __builtin_amdgcn_s_setprio(0);
    }
    __syncthreads();                   // drains prefetch; guards dbuf swap
  }

  // ---- epilogue: D row = ch = mt*32 + (r&3)+8*(r>>2)+4*half, col = pixel ----
  const int h = h0 + wr;
  #pragma unroll
  for (int mt = 0; mt < 4; ++mt) {
    #pragma unroll
    for (int r = 0; r < 16; ++r) {
      const int cl = mt * 32 + (r & 3) + 8 * (r >> 2) + 4 * half;
      const int bi = bsh[cl];
      const float sc = ssh[cl];
      int* ob = out + (((size_t)(n_img * KOUT + ktb * 128 + cl)) * HO + h) * WO;
      #pragma unroll
      for (int nt = 0; nt < 2; ++nt) {
        const int w = nt * 32 + p0;
        if (w < WO) {
          float v = (float)(acc[mt][nt][r] + bi) * sc;
          v = rintf(v);                          // round-half-even == jnp.round
          v = fminf(fmaxf(v, -128.0f), 127.0f);
          ob[w] = (int)v;
        }
      }
    }
  }
}

extern "C" void kernel_launch(void* const* d_in, const int* in_sizes, int n_in,
                              void* d_out, int out_size, void* d_ws, size_t ws_size,
                              hipStream_t stream) {
  const int* x = (const int*)d_in[0];
  const int* wgt = (const int*)d_in[1];
  const int* bias = (const int*)d_in[2];
  const float* wscale = (const float*)d_in[3];
  int* out = (int*)d_out;

  int8_t* xp = (int8_t*)d_ws;                               // 13,780,992 B
  int8_t* wq = (int8_t*)d_ws + (size_t)NB * HP * ROWB;      // 294,912 B

  pack_x_kernel<<<dim3(HP, NB), 256, 0, stream>>>(x, xp);
  pack_w_kernel<<<288, 256, 0, stream>>>(wgt, wq);
  conv_kernel<<<dim3(7, 32, 2), 512, 0, stream>>>(xp, wq, bias, wscale, out);
}